// Round 9
// baseline (215.879 us; speedup 1.0000x reference)
//
#include <hip/hip_runtime.h>

#define T_  2
#define N_  10000
#define C_  64
#define H_  4
#define Co_ 64
#define E_  160000
#define HC_ 256          // H*Co
#define NEG_SLOPE 0.2f
#define LN_EPS 1e-5f
#define GEMM_BLOCKS (T_ * N_ / 16)   // 1250

__device__ __forceinline__ float lrelu(float v) {
    return fmaxf(v, NEG_SLOPE * v);      // valid since NEG_SLOPE < 1
}
__device__ __forceinline__ float bf2f(unsigned short u) {
    return __uint_as_float((unsigned)u << 16);
}
__device__ __forceinline__ unsigned short f2bf(float f) {   // RNE
    const unsigned u = __float_as_uint(f);
    return (unsigned short)((u + 0x7FFFu + ((u >> 16) & 1u)) >> 16);
}

// ---- Fused: 1250 gemm blocks (x@Wl->bf16 xl, x@Wr->f32 xr) + 1 block doing
// dst histogram + exclusive scan in LDS (runs concurrently with gemm).
__global__ __launch_bounds__(256) void fused_pre(
        const float* __restrict__ x, const float* __restrict__ Wl,
        const float* __restrict__ bl, const float* __restrict__ Wr,
        const float* __restrict__ br, unsigned short* __restrict__ xlb,
        float* __restrict__ xr, const int* __restrict__ dst,
        int* __restrict__ row_start, int* __restrict__ cursor) {
    __shared__ __align__(16) char smem[40992];   // 40 KB union
    const int tid = threadIdx.x;

    if (blockIdx.x < GEMM_BLOCKS) {
        // ---------------- GEMM part: 16 rows per block ----------------
        float4* xs = (float4*)smem;           // 16 rows x 16 float4, 4 KB
        const int r0   = blockIdx.x * 16;
        const int half = tid >> 7;            // row group 0/1
        const int q    = tid & 127;
        const int mat  = q >> 6;              // 0=Wl->xl(bf16), 1=Wr->xr(f32)
        const int col4 = q & 63;              // float4 column group 0..63
        const float* W  = mat ? Wr : Wl;
        const float* bv = mat ? br : bl;

        xs[tid] = ((const float4*)(x + (size_t)r0 * C_))[tid];
        __syncthreads();

        const float4 b4 = ((const float4*)bv)[col4];
        float4 acc[8];
        #pragma unroll
        for (int r = 0; r < 8; ++r) acc[r] = b4;

        const int rbase = half * 8;
        #pragma unroll 2
        for (int c4 = 0; c4 < 16; ++c4) {
            const float4 w0 = ((const float4*)(W + (size_t)(c4 * 4 + 0) * HC_))[col4];
            const float4 w1 = ((const float4*)(W + (size_t)(c4 * 4 + 1) * HC_))[col4];
            const float4 w2 = ((const float4*)(W + (size_t)(c4 * 4 + 2) * HC_))[col4];
            const float4 w3 = ((const float4*)(W + (size_t)(c4 * 4 + 3) * HC_))[col4];
            #pragma unroll
            for (int r = 0; r < 8; ++r) {
                const float4 xv = xs[(rbase + r) * 16 + c4];
                acc[r].x = fmaf(xv.x, w0.x, acc[r].x);
                acc[r].y = fmaf(xv.x, w0.y, acc[r].y);
                acc[r].z = fmaf(xv.x, w0.z, acc[r].z);
                acc[r].w = fmaf(xv.x, w0.w, acc[r].w);
                acc[r].x = fmaf(xv.y, w1.x, acc[r].x);
                acc[r].y = fmaf(xv.y, w1.y, acc[r].y);
                acc[r].z = fmaf(xv.y, w1.z, acc[r].z);
                acc[r].w = fmaf(xv.y, w1.w, acc[r].w);
                acc[r].x = fmaf(xv.z, w2.x, acc[r].x);
                acc[r].y = fmaf(xv.z, w2.y, acc[r].y);
                acc[r].z = fmaf(xv.z, w2.z, acc[r].z);
                acc[r].w = fmaf(xv.z, w2.w, acc[r].w);
                acc[r].x = fmaf(xv.w, w3.x, acc[r].x);
                acc[r].y = fmaf(xv.w, w3.y, acc[r].y);
                acc[r].z = fmaf(xv.w, w3.z, acc[r].z);
                acc[r].w = fmaf(xv.w, w3.w, acc[r].w);
            }
        }
        if (mat) {
            #pragma unroll
            for (int r = 0; r < 8; ++r)
                ((float4*)(xr + (size_t)(r0 + rbase + r) * HC_))[col4] = acc[r];
        } else {
            #pragma unroll
            for (int r = 0; r < 8; ++r) {
                ushort4 u;
                u.x = f2bf(acc[r].x); u.y = f2bf(acc[r].y);
                u.z = f2bf(acc[r].z); u.w = f2bf(acc[r].w);
                ((ushort4*)(xlb + (size_t)(r0 + rbase + r) * HC_))[col4] = u;
            }
        }
    } else {
        // ------------- scanhist part: one block, 256 threads -------------
        int* cnt  = (int*)smem;               // N_ ints = 40 KB
        int* wsum = (int*)(smem + 40000);     // 4 wave totals
        const int lane = tid & 63, wave = tid >> 6;

        for (int i = tid; i < N_; i += 256) cnt[i] = 0;
        __syncthreads();
        const int4* d4 = (const int4*)dst;    // E_ % 4 == 0
        for (int i = tid; i < E_ / 4; i += 256) {
            const int4 v = d4[i];
            atomicAdd(&cnt[v.x], 1);
            atomicAdd(&cnt[v.y], 1);
            atomicAdd(&cnt[v.z], 1);
            atomicAdd(&cnt[v.w], 1);
        }
        __syncthreads();
        // pass 1: per-thread total over 40 contiguous counts
        const int base = tid * 40;            // 256*40 >= N_
        int s = 0;
        for (int i = 0; i < 40; ++i) {
            const int idx = base + i;
            if (idx < N_) s += cnt[idx];
        }
        int incl = s;                         // wave inclusive scan
        #pragma unroll
        for (int off = 1; off < 64; off <<= 1) {
            const int u = __shfl_up(incl, off, 64);
            if (lane >= off) incl += u;
        }
        if (lane == 63) wsum[wave] = incl;
        __syncthreads();
        if (wave == 0 && lane < 4) {
            const int v = wsum[lane];
            int iv = v;
            #pragma unroll
            for (int off = 1; off < 4; off <<= 1) {
                const int u = __shfl_up(iv, off, 64);
                if (lane >= off) iv += u;
            }
            wsum[lane] = iv - v;              // exclusive
            if (lane == 3) row_start[N_] = iv;
        }
        __syncthreads();
        // pass 2: write running prefix to row_start and cursor
        int run = wsum[wave] + (incl - s);
        for (int i = 0; i < 40; ++i) {
            const int idx = base + i;
            if (idx < N_) {
                const int c = cnt[idx];
                row_start[idx] = run;
                cursor[idx]    = run;
                run += c;
            }
        }
    }
}

// ---- scatter edge srcs into dst-sorted order (cursor pre-seeded)
__global__ __launch_bounds__(256) void scatter_kernel(
        const int* __restrict__ src, const int* __restrict__ dst,
        int* __restrict__ cursor, int* __restrict__ perm_src) {
    const int e = blockIdx.x * 256 + threadIdx.x;
    if (e >= E_) return;
    const int pos = atomicAdd(&cursor[dst[e]], 1);
    perm_src[pos] = src[e];
}

// ---- Fused per-node attention: one wave per (t,n), 4 edges in flight,
// xl gathered as bf16 (half traffic)
__global__ __launch_bounds__(256) void node_agg(
        const unsigned short* __restrict__ xlb, const float* __restrict__ xr,
        const float* __restrict__ att, const int* __restrict__ perm_src,
        const int* __restrict__ row_start, float* __restrict__ agg) {
    const int wid  = blockIdx.x * 4 + (threadIdx.x >> 6);   // t*N + n
    const int lane = threadIdx.x & 63;
    const int t = wid / N_, n = wid % N_;
    const int beg = row_start[n], end = row_start[n + 1];
    const float4 xi = ((const float4*)&xr[(size_t)wid * HC_])[lane];
    const float4 av = ((const float4*)att)[lane];
    const unsigned short* xlt = xlb + (size_t)t * N_ * HC_;

    float m = -INFINITY, s = 0.f;
    float4 acc = make_float4(0.f, 0.f, 0.f, 0.f);

    for (int base = beg; base < end; base += 64) {
        const int cnt = min(64, end - base);
        const int myidx = (lane < cnt) ? perm_src[base + lane] : 0;
        for (int k = 0; k < cnt; k += 4) {
            const int i0 = __shfl(myidx, k + 0, 64);
            const int i1 = __shfl(myidx, k + 1, 64);
            const int i2 = __shfl(myidx, k + 2, 64);
            const int i3 = __shfl(myidx, k + 3, 64);
            const ushort4 u0 = ((const ushort4*)&xlt[(size_t)i0 * HC_])[lane];
            const ushort4 u1 = ((const ushort4*)&xlt[(size_t)i1 * HC_])[lane];
            const ushort4 u2 = ((const ushort4*)&xlt[(size_t)i2 * HC_])[lane];
            const ushort4 u3 = ((const ushort4*)&xlt[(size_t)i3 * HC_])[lane];
            const float4 c0 = make_float4(bf2f(u0.x), bf2f(u0.y), bf2f(u0.z), bf2f(u0.w));
            const float4 c1 = make_float4(bf2f(u1.x), bf2f(u1.y), bf2f(u1.z), bf2f(u1.w));
            const float4 c2 = make_float4(bf2f(u2.x), bf2f(u2.y), bf2f(u2.z), bf2f(u2.w));
            const float4 c3 = make_float4(bf2f(u3.x), bf2f(u3.y), bf2f(u3.z), bf2f(u3.w));
            // four independent dots over this lane's 4 channels
            float p0 =      lrelu(xi.x + c0.x) * av.x;
            p0 = fmaf(lrelu(xi.y + c0.y), av.y, p0);
            p0 = fmaf(lrelu(xi.z + c0.z), av.z, p0);
            p0 = fmaf(lrelu(xi.w + c0.w), av.w, p0);
            float p1 =      lrelu(xi.x + c1.x) * av.x;
            p1 = fmaf(lrelu(xi.y + c1.y), av.y, p1);
            p1 = fmaf(lrelu(xi.z + c1.z), av.z, p1);
            p1 = fmaf(lrelu(xi.w + c1.w), av.w, p1);
            float p2 =      lrelu(xi.x + c2.x) * av.x;
            p2 = fmaf(lrelu(xi.y + c2.y), av.y, p2);
            p2 = fmaf(lrelu(xi.z + c2.z), av.z, p2);
            p2 = fmaf(lrelu(xi.w + c2.w), av.w, p2);
            float p3 =      lrelu(xi.x + c3.x) * av.x;
            p3 = fmaf(lrelu(xi.y + c3.y), av.y, p3);
            p3 = fmaf(lrelu(xi.z + c3.z), av.z, p3);
            p3 = fmaf(lrelu(xi.w + c3.w), av.w, p3);
            // interleaved 16-lane head reductions
            #pragma unroll
            for (int o = 1; o < 16; o <<= 1) {
                p0 += __shfl_xor(p0, o, 64);
                p1 += __shfl_xor(p1, o, 64);
                p2 += __shfl_xor(p2, o, 64);
                p3 += __shfl_xor(p3, o, 64);
            }
            // mask padding edges (cnt is wave-uniform)
            if (k + 1 >= cnt) p1 = -INFINITY;
            if (k + 2 >= cnt) p2 = -INFINITY;
            if (k + 3 >= cnt) p3 = -INFINITY;
            // one shared softmax rescale per group of 4
            const float gm = fmaxf(fmaxf(p0, p1), fmaxf(p2, p3));
            const float m_new = fmaxf(m, gm);
            const float sc = __expf(m - m_new);
            const float w0 = __expf(p0 - m_new);
            const float w1 = __expf(p1 - m_new);   // exp(-inf)=0 for padding
            const float w2 = __expf(p2 - m_new);
            const float w3 = __expf(p3 - m_new);
            s = fmaf(s, sc, w0 + w1 + w2 + w3);
            acc.x = fmaf(acc.x, sc,
                    fmaf(w0, c0.x, fmaf(w1, c1.x, fmaf(w2, c2.x, w3 * c3.x))));
            acc.y = fmaf(acc.y, sc,
                    fmaf(w0, c0.y, fmaf(w1, c1.y, fmaf(w2, c2.y, w3 * c3.y))));
            acc.z = fmaf(acc.z, sc,
                    fmaf(w0, c0.z, fmaf(w1, c1.z, fmaf(w2, c2.z, w3 * c3.z))));
            acc.w = fmaf(acc.w, sc,
                    fmaf(w0, c0.w, fmaf(w1, c1.w, fmaf(w2, c2.w, w3 * c3.w))));
            m = m_new;
        }
    }
    if (end > beg) {
        const float inv = 1.f / s;
        acc.x *= inv; acc.y *= inv; acc.z *= inv; acc.w *= inv;
    }
    ((float4*)&agg[(size_t)wid * HC_])[lane] = acc;
}

// ---- Pass E: relu(agg+bias) @ W_proj + b_proj + x -> LN -> relu
__global__ __launch_bounds__(256) void epilogue(
        const float* __restrict__ agg, const float* __restrict__ bias,
        const float* __restrict__ Wp, const float* __restrict__ bp,
        const float* __restrict__ x, const float* __restrict__ gamma,
        const float* __restrict__ beta, float* __restrict__ out) {
    __shared__ float sh[32 * HC_];       // 32 KB
    const int r0  = blockIdx.x * 32;
    const int tid = threadIdx.x;
    #pragma unroll
    for (int i = 0; i < 8; ++i) {
        const int slot = i * 256 + tid;          // float4 index
        const int r = slot >> 6, f4 = slot & 63;
        float4 v = ((const float4*)&agg[(size_t)(r0 + r) * HC_])[f4];
        const float4 b = ((const float4*)bias)[f4];
        v.x = fmaxf(v.x + b.x, 0.f); v.y = fmaxf(v.y + b.y, 0.f);
        v.z = fmaxf(v.z + b.z, 0.f); v.w = fmaxf(v.w + b.w, 0.f);
        ((float4*)sh)[slot] = v;
    }
    __syncthreads();
    const int wave = tid >> 6, o = tid & 63;
    const int rbase = wave * 8;                  // local row base
    const float bpo = bp[o];
    float acc[8];
    #pragma unroll
    for (int r = 0; r < 8; ++r)
        acc[r] = bpo + x[(size_t)(r0 + rbase + r) * C_ + o];
    for (int k = 0; k < HC_; k += 4) {
        const float w0 = Wp[(k + 0) * Co_ + o];
        const float w1 = Wp[(k + 1) * Co_ + o];
        const float w2 = Wp[(k + 2) * Co_ + o];
        const float w3 = Wp[(k + 3) * Co_ + o];
        #pragma unroll
        for (int r = 0; r < 8; ++r) {
            const float4 s4 = ((const float4*)&sh[(rbase + r) * HC_])[k >> 2];
            acc[r] = fmaf(s4.x, w0, acc[r]);
            acc[r] = fmaf(s4.y, w1, acc[r]);
            acc[r] = fmaf(s4.z, w2, acc[r]);
            acc[r] = fmaf(s4.w, w3, acc[r]);
        }
    }
    const float go = gamma[o], bo = beta[o];
    #pragma unroll
    for (int r = 0; r < 8; ++r) {
        float s1 = acc[r];
        #pragma unroll
        for (int off = 1; off < 64; off <<= 1) s1 += __shfl_xor(s1, off, 64);
        const float mu = s1 * (1.f / 64.f);
        const float dv = acc[r] - mu;
        float s2 = dv * dv;
        #pragma unroll
        for (int off = 1; off < 64; off <<= 1) s2 += __shfl_xor(s2, off, 64);
        const float var = s2 * (1.f / 64.f);
        const float y = dv * rsqrtf(var + LN_EPS) * go + bo;
        out[(size_t)(r0 + rbase + r) * C_ + o] = fmaxf(y, 0.f);
    }
}

extern "C" void kernel_launch(void* const* d_in, const int* in_sizes, int n_in,
                              void* d_out, int out_size, void* d_ws, size_t ws_size,
                              hipStream_t stream) {
    const float* x    = (const float*)d_in[0];
    const int*   ei   = (const int*)  d_in[1];
    const float* Wl   = (const float*)d_in[2];
    const float* bl   = (const float*)d_in[3];
    const float* Wr   = (const float*)d_in[4];
    const float* br   = (const float*)d_in[5];
    const float* att  = (const float*)d_in[6];
    const float* bias = (const float*)d_in[7];
    const float* Wp   = (const float*)d_in[8];
    const float* bp   = (const float*)d_in[9];
    const float* gam  = (const float*)d_in[10];
    const float* bet  = (const float*)d_in[11];
    const int* src = ei;            // edge_index[0]
    const int* dst = ei + E_;       // edge_index[1]

    float* ws = (float*)d_ws;
    unsigned short* xlb = (unsigned short*)ws;             // T*N*HC bf16
    float* xr  = (float*)(xlb + (size_t)T_ * N_ * HC_);    // T*N*HC f32
    float* agg = xr + (size_t)T_ * N_ * HC_;               // T*N*HC f32
    int* row_start = (int*)(agg + (size_t)T_ * N_ * HC_);  // N+1
    int* cursor    = row_start + (N_ + 1);                 // N
    int* perm_src  = cursor + N_;                          // E

    fused_pre<<<GEMM_BLOCKS + 1, 256, 0, stream>>>(
        x, Wl, bl, Wr, br, xlb, xr, dst, row_start, cursor);
    scatter_kernel<<<(E_ + 255) / 256, 256, 0, stream>>>(src, dst, cursor,
                                                         perm_src);
    node_agg<<<T_ * N_ / 4,  256, 0, stream>>>(xlb, xr, att, perm_src,
                                               row_start, agg);
    epilogue<<<T_ * N_ / 32, 256, 0, stream>>>(agg, bias, Wp, bp, x, gam, bet,
                                               (float*)d_out);
}

// Round 10
// 187.563 us; speedup vs baseline: 1.1510x; 1.1510x over previous
//
#include <hip/hip_runtime.h>

#define T_  2
#define N_  10000
#define C_  64
#define H_  4
#define Co_ 64
#define E_  160000
#define HC_ 256          // H*Co
#define NEG_SLOPE 0.2f
#define LN_EPS 1e-5f
#define SCAT_BLOCKS ((E_ + 255) / 256)   // 625
#define GEMM_BLOCKS (T_ * N_ / 16)       // 1250

__device__ __forceinline__ float lrelu(float v) {
    return fmaxf(v, NEG_SLOPE * v);      // valid since NEG_SLOPE < 1
}
__device__ __forceinline__ float bf2f(unsigned short u) {
    return __uint_as_float((unsigned)u << 16);
}
__device__ __forceinline__ unsigned short f2bf(float f) {   // RNE
    const unsigned u = __float_as_uint(f);
    return (unsigned short)((u + 0x7FFFu + ((u >> 16) & 1u)) >> 16);
}

// ---- hist: parallel global-atomic histogram of dst
__global__ __launch_bounds__(256) void hist_kernel(
        const int* __restrict__ dst, int* __restrict__ count) {
    const int e = blockIdx.x * 256 + threadIdx.x;
    if (e < E_) atomicAdd(&count[dst[e]], 1);
}

// ---- scan: shuffle-based exclusive scan; seeds cursor = row_start
__global__ __launch_bounds__(1024) void scan_kernel(
        const int* __restrict__ count, int* __restrict__ row_start,
        int* __restrict__ cursor) {
    __shared__ int wsum[16];
    const int tid  = threadIdx.x;
    const int lane = tid & 63, wave = tid >> 6;
    const int base = tid * 10;             // 1024*10 >= N_
    int local[10];
    int s = 0;
    #pragma unroll
    for (int i = 0; i < 10; ++i) {
        const int idx = base + i;
        const int v = (idx < N_) ? count[idx] : 0;
        local[i] = s;
        s += v;
    }
    int incl = s;                          // wave inclusive scan of totals
    #pragma unroll
    for (int off = 1; off < 64; off <<= 1) {
        const int u = __shfl_up(incl, off, 64);
        if (lane >= off) incl += u;
    }
    if (lane == 63) wsum[wave] = incl;
    __syncthreads();
    if (wave == 0 && lane < 16) {
        const int v = wsum[lane];
        int iv = v;
        #pragma unroll
        for (int off = 1; off < 16; off <<= 1) {
            const int u = __shfl_up(iv, off, 64);
            if (lane >= off) iv += u;
        }
        wsum[lane] = iv - v;               // exclusive
        if (lane == 15) row_start[N_] = iv;
    }
    __syncthreads();
    const int tpre = wsum[wave] + (incl - s);
    #pragma unroll
    for (int i = 0; i < 10; ++i) {
        const int idx = base + i;
        if (idx < N_) {
            const int st = tpre + local[i];
            row_start[idx] = st;
            cursor[idx]    = st;
        }
    }
}

// ---- Fused scatter (blocks 0..624) + gemm (blocks 625..1874).
// Independent work, both wide; overlapping them saves a dispatch.
__global__ __launch_bounds__(256) void scat_gemm(
        const int* __restrict__ src, const int* __restrict__ dst,
        int* __restrict__ cursor, int* __restrict__ perm_src,
        const float* __restrict__ x, const float* __restrict__ Wl,
        const float* __restrict__ bl, const float* __restrict__ Wr,
        const float* __restrict__ br, unsigned short* __restrict__ xlb,
        float* __restrict__ xr) {
    const int tid = threadIdx.x;
    if (blockIdx.x < SCAT_BLOCKS) {
        const int e = blockIdx.x * 256 + tid;
        if (e < E_) {
            const int pos = atomicAdd(&cursor[dst[e]], 1);
            perm_src[pos] = src[e];
        }
        return;
    }
    // ---------------- GEMM part: 16 rows per block ----------------
    __shared__ float4 xs[16 * 16];        // 16 rows x 16 float4 (=64 c), 4 KB
    const int r0   = (blockIdx.x - SCAT_BLOCKS) * 16;
    const int half = tid >> 7;            // row group 0/1
    const int q    = tid & 127;
    const int mat  = q >> 6;              // 0=Wl->xl(bf16), 1=Wr->xr(f32)
    const int col4 = q & 63;              // float4 column group 0..63
    const float* W  = mat ? Wr : Wl;
    const float* bv = mat ? br : bl;

    xs[tid] = ((const float4*)(x + (size_t)r0 * C_))[tid];
    __syncthreads();

    const float4 b4 = ((const float4*)bv)[col4];
    float4 acc[8];
    #pragma unroll
    for (int r = 0; r < 8; ++r) acc[r] = b4;

    const int rbase = half * 8;
    #pragma unroll 2
    for (int c4 = 0; c4 < 16; ++c4) {
        const float4 w0 = ((const float4*)(W + (size_t)(c4 * 4 + 0) * HC_))[col4];
        const float4 w1 = ((const float4*)(W + (size_t)(c4 * 4 + 1) * HC_))[col4];
        const float4 w2 = ((const float4*)(W + (size_t)(c4 * 4 + 2) * HC_))[col4];
        const float4 w3 = ((const float4*)(W + (size_t)(c4 * 4 + 3) * HC_))[col4];
        #pragma unroll
        for (int r = 0; r < 8; ++r) {
            const float4 xv = xs[(rbase + r) * 16 + c4];
            acc[r].x = fmaf(xv.x, w0.x, acc[r].x);
            acc[r].y = fmaf(xv.x, w0.y, acc[r].y);
            acc[r].z = fmaf(xv.x, w0.z, acc[r].z);
            acc[r].w = fmaf(xv.x, w0.w, acc[r].w);
            acc[r].x = fmaf(xv.y, w1.x, acc[r].x);
            acc[r].y = fmaf(xv.y, w1.y, acc[r].y);
            acc[r].z = fmaf(xv.y, w1.z, acc[r].z);
            acc[r].w = fmaf(xv.y, w1.w, acc[r].w);
            acc[r].x = fmaf(xv.z, w2.x, acc[r].x);
            acc[r].y = fmaf(xv.z, w2.y, acc[r].y);
            acc[r].z = fmaf(xv.z, w2.z, acc[r].z);
            acc[r].w = fmaf(xv.z, w2.w, acc[r].w);
            acc[r].x = fmaf(xv.w, w3.x, acc[r].x);
            acc[r].y = fmaf(xv.w, w3.y, acc[r].y);
            acc[r].z = fmaf(xv.w, w3.z, acc[r].z);
            acc[r].w = fmaf(xv.w, w3.w, acc[r].w);
        }
    }
    if (mat) {
        #pragma unroll
        for (int r = 0; r < 8; ++r)
            ((float4*)(xr + (size_t)(r0 + rbase + r) * HC_))[col4] = acc[r];
    } else {
        #pragma unroll
        for (int r = 0; r < 8; ++r) {
            ushort4 u;
            u.x = f2bf(acc[r].x); u.y = f2bf(acc[r].y);
            u.z = f2bf(acc[r].z); u.w = f2bf(acc[r].w);
            ((ushort4*)(xlb + (size_t)(r0 + rbase + r) * HC_))[col4] = u;
        }
    }
}

// ---- Fused per-node attention: one wave per (t,n), 4 edges in flight,
// xl gathered as bf16; agg written as bf16
__global__ __launch_bounds__(256) void node_agg(
        const unsigned short* __restrict__ xlb, const float* __restrict__ xr,
        const float* __restrict__ att, const int* __restrict__ perm_src,
        const int* __restrict__ row_start, unsigned short* __restrict__ aggb) {
    const int wid  = blockIdx.x * 4 + (threadIdx.x >> 6);   // t*N + n
    const int lane = threadIdx.x & 63;
    const int t = wid / N_, n = wid % N_;
    const int beg = row_start[n], end = row_start[n + 1];
    const float4 xi = ((const float4*)&xr[(size_t)wid * HC_])[lane];
    const float4 av = ((const float4*)att)[lane];
    const unsigned short* xlt = xlb + (size_t)t * N_ * HC_;

    float m = -INFINITY, s = 0.f;
    float4 acc = make_float4(0.f, 0.f, 0.f, 0.f);

    for (int base = beg; base < end; base += 64) {
        const int cnt = min(64, end - base);
        const int myidx = (lane < cnt) ? perm_src[base + lane] : 0;
        for (int k = 0; k < cnt; k += 4) {
            const int i0 = __shfl(myidx, k + 0, 64);
            const int i1 = __shfl(myidx, k + 1, 64);
            const int i2 = __shfl(myidx, k + 2, 64);
            const int i3 = __shfl(myidx, k + 3, 64);
            const ushort4 u0 = ((const ushort4*)&xlt[(size_t)i0 * HC_])[lane];
            const ushort4 u1 = ((const ushort4*)&xlt[(size_t)i1 * HC_])[lane];
            const ushort4 u2 = ((const ushort4*)&xlt[(size_t)i2 * HC_])[lane];
            const ushort4 u3 = ((const ushort4*)&xlt[(size_t)i3 * HC_])[lane];
            const float4 c0 = make_float4(bf2f(u0.x), bf2f(u0.y), bf2f(u0.z), bf2f(u0.w));
            const float4 c1 = make_float4(bf2f(u1.x), bf2f(u1.y), bf2f(u1.z), bf2f(u1.w));
            const float4 c2 = make_float4(bf2f(u2.x), bf2f(u2.y), bf2f(u2.z), bf2f(u2.w));
            const float4 c3 = make_float4(bf2f(u3.x), bf2f(u3.y), bf2f(u3.z), bf2f(u3.w));
            // four independent dots over this lane's 4 channels
            float p0 =      lrelu(xi.x + c0.x) * av.x;
            p0 = fmaf(lrelu(xi.y + c0.y), av.y, p0);
            p0 = fmaf(lrelu(xi.z + c0.z), av.z, p0);
            p0 = fmaf(lrelu(xi.w + c0.w), av.w, p0);
            float p1 =      lrelu(xi.x + c1.x) * av.x;
            p1 = fmaf(lrelu(xi.y + c1.y), av.y, p1);
            p1 = fmaf(lrelu(xi.z + c1.z), av.z, p1);
            p1 = fmaf(lrelu(xi.w + c1.w), av.w, p1);
            float p2 =      lrelu(xi.x + c2.x) * av.x;
            p2 = fmaf(lrelu(xi.y + c2.y), av.y, p2);
            p2 = fmaf(lrelu(xi.z + c2.z), av.z, p2);
            p2 = fmaf(lrelu(xi.w + c2.w), av.w, p2);
            float p3 =      lrelu(xi.x + c3.x) * av.x;
            p3 = fmaf(lrelu(xi.y + c3.y), av.y, p3);
            p3 = fmaf(lrelu(xi.z + c3.z), av.z, p3);
            p3 = fmaf(lrelu(xi.w + c3.w), av.w, p3);
            // interleaved 16-lane head reductions
            #pragma unroll
            for (int o = 1; o < 16; o <<= 1) {
                p0 += __shfl_xor(p0, o, 64);
                p1 += __shfl_xor(p1, o, 64);
                p2 += __shfl_xor(p2, o, 64);
                p3 += __shfl_xor(p3, o, 64);
            }
            // mask padding edges (cnt is wave-uniform)
            if (k + 1 >= cnt) p1 = -INFINITY;
            if (k + 2 >= cnt) p2 = -INFINITY;
            if (k + 3 >= cnt) p3 = -INFINITY;
            // one shared softmax rescale per group of 4
            const float gm = fmaxf(fmaxf(p0, p1), fmaxf(p2, p3));
            const float m_new = fmaxf(m, gm);
            const float sc = __expf(m - m_new);
            const float w0 = __expf(p0 - m_new);
            const float w1 = __expf(p1 - m_new);   // exp(-inf)=0 for padding
            const float w2 = __expf(p2 - m_new);
            const float w3 = __expf(p3 - m_new);
            s = fmaf(s, sc, w0 + w1 + w2 + w3);
            acc.x = fmaf(acc.x, sc,
                    fmaf(w0, c0.x, fmaf(w1, c1.x, fmaf(w2, c2.x, w3 * c3.x))));
            acc.y = fmaf(acc.y, sc,
                    fmaf(w0, c0.y, fmaf(w1, c1.y, fmaf(w2, c2.y, w3 * c3.y))));
            acc.z = fmaf(acc.z, sc,
                    fmaf(w0, c0.z, fmaf(w1, c1.z, fmaf(w2, c2.z, w3 * c3.z))));
            acc.w = fmaf(acc.w, sc,
                    fmaf(w0, c0.w, fmaf(w1, c1.w, fmaf(w2, c2.w, w3 * c3.w))));
            m = m_new;
        }
    }
    if (end > beg) {
        const float inv = 1.f / s;
        acc.x *= inv; acc.y *= inv; acc.z *= inv; acc.w *= inv;
    }
    ushort4 o4;
    o4.x = f2bf(acc.x); o4.y = f2bf(acc.y);
    o4.z = f2bf(acc.z); o4.w = f2bf(acc.w);
    ((ushort4*)&aggb[(size_t)wid * HC_])[lane] = o4;
}

// ---- Pass E: relu(agg+bias) @ W_proj + b_proj + x -> LN -> relu
__global__ __launch_bounds__(256) void epilogue(
        const unsigned short* __restrict__ aggb, const float* __restrict__ bias,
        const float* __restrict__ Wp, const float* __restrict__ bp,
        const float* __restrict__ x, const float* __restrict__ gamma,
        const float* __restrict__ beta, float* __restrict__ out) {
    __shared__ float sh[32 * HC_];       // 32 KB
    const int r0  = blockIdx.x * 32;
    const int tid = threadIdx.x;
    #pragma unroll
    for (int i = 0; i < 8; ++i) {
        const int slot = i * 256 + tid;          // ushort4/float4 index
        const int r = slot >> 6, f4 = slot & 63;
        const ushort4 u = ((const ushort4*)&aggb[(size_t)(r0 + r) * HC_])[f4];
        const float4 b = ((const float4*)bias)[f4];
        float4 v;
        v.x = fmaxf(bf2f(u.x) + b.x, 0.f); v.y = fmaxf(bf2f(u.y) + b.y, 0.f);
        v.z = fmaxf(bf2f(u.z) + b.z, 0.f); v.w = fmaxf(bf2f(u.w) + b.w, 0.f);
        ((float4*)sh)[slot] = v;
    }
    __syncthreads();
    const int wave = tid >> 6, o = tid & 63;
    const int rbase = wave * 8;                  // local row base
    const float bpo = bp[o];
    float acc[8];
    #pragma unroll
    for (int r = 0; r < 8; ++r)
        acc[r] = bpo + x[(size_t)(r0 + rbase + r) * C_ + o];
    for (int k = 0; k < HC_; k += 4) {
        const float w0 = Wp[(k + 0) * Co_ + o];
        const float w1 = Wp[(k + 1) * Co_ + o];
        const float w2 = Wp[(k + 2) * Co_ + o];
        const float w3 = Wp[(k + 3) * Co_ + o];
        #pragma unroll
        for (int r = 0; r < 8; ++r) {
            const float4 s4 = ((const float4*)&sh[(rbase + r) * HC_])[k >> 2];
            acc[r] = fmaf(s4.x, w0, acc[r]);
            acc[r] = fmaf(s4.y, w1, acc[r]);
            acc[r] = fmaf(s4.z, w2, acc[r]);
            acc[r] = fmaf(s4.w, w3, acc[r]);
        }
    }
    const float go = gamma[o], bo = beta[o];
    #pragma unroll
    for (int r = 0; r < 8; ++r) {
        float s1 = acc[r];
        #pragma unroll
        for (int off = 1; off < 64; off <<= 1) s1 += __shfl_xor(s1, off, 64);
        const float mu = s1 * (1.f / 64.f);
        const float dv = acc[r] - mu;
        float s2 = dv * dv;
        #pragma unroll
        for (int off = 1; off < 64; off <<= 1) s2 += __shfl_xor(s2, off, 64);
        const float var = s2 * (1.f / 64.f);
        const float y = dv * rsqrtf(var + LN_EPS) * go + bo;
        out[(size_t)(r0 + rbase + r) * C_ + o] = fmaxf(y, 0.f);
    }
}

extern "C" void kernel_launch(void* const* d_in, const int* in_sizes, int n_in,
                              void* d_out, int out_size, void* d_ws, size_t ws_size,
                              hipStream_t stream) {
    const float* x    = (const float*)d_in[0];
    const int*   ei   = (const int*)  d_in[1];
    const float* Wl   = (const float*)d_in[2];
    const float* bl   = (const float*)d_in[3];
    const float* Wr   = (const float*)d_in[4];
    const float* br   = (const float*)d_in[5];
    const float* att  = (const float*)d_in[6];
    const float* bias = (const float*)d_in[7];
    const float* Wp   = (const float*)d_in[8];
    const float* bp   = (const float*)d_in[9];
    const float* gam  = (const float*)d_in[10];
    const float* bet  = (const float*)d_in[11];
    const int* src = ei;            // edge_index[0]
    const int* dst = ei + E_;       // edge_index[1]

    char* ws = (char*)d_ws;
    unsigned short* xlb  = (unsigned short*)ws;                   // T*N*HC bf16
    float*          xr   = (float*)(xlb + (size_t)T_ * N_ * HC_); // T*N*HC f32
    unsigned short* aggb = (unsigned short*)(xr + (size_t)T_ * N_ * HC_); // bf16
    int* row_start = (int*)(aggb + (size_t)T_ * N_ * HC_);        // N+1
    int* count     = row_start + (N_ + 1);                        // N
    int* cursor    = count + N_;                                  // N
    int* perm_src  = cursor + N_;                                 // E

    hipMemsetAsync(count, 0, N_ * sizeof(int), stream);

    hist_kernel<<<SCAT_BLOCKS, 256, 0, stream>>>(dst, count);
    scan_kernel<<<1, 1024, 0, stream>>>(count, row_start, cursor);
    scat_gemm  <<<SCAT_BLOCKS + GEMM_BLOCKS, 256, 0, stream>>>(
        src, dst, cursor, perm_src, x, Wl, bl, Wr, br, xlb, xr);
    node_agg   <<<T_ * N_ / 4,  256, 0, stream>>>(xlb, xr, att, perm_src,
                                                  row_start, aggb);
    epilogue   <<<T_ * N_ / 32, 256, 0, stream>>>(aggb, bias, Wp, bp, x,
                                                  gam, bet, (float*)d_out);
}